// Round 11
// baseline (70.171 us; speedup 1.0000x reference)
//
#include <hip/hip_runtime.h>
#include <hip/hip_bf16.h>
#include <hip/hip_fp16.h>
#include <stdint.h>

typedef __bf16 bf16x8 __attribute__((ext_vector_type(8)));
typedef float  f32x4  __attribute__((ext_vector_type(4)));
typedef _Float16 h2   __attribute__((ext_vector_type(2)));
typedef int    i32x4  __attribute__((ext_vector_type(4)));

#define MAIN_BLOCKS 256
#define MAIN_THREADS 1024

// R6 inner loop (proven: 53us, passing), relaunched as 256 blocks x 1024 thr.
// R10 probe result: effective core clock ~0.9-1.2 GHz (idle DVFS; tiny
// dispatches never ramp). At 1.17GHz the kernel is VALU-issue-bound with
// ~145 instr/tile across ALL past variants (R5-R8 nulls explained). Busy is
// only ~52% though: avg residency 1.5 waves/SIMD << the 4 allowed by
// VGPR=100. This round: 1 block/CU (16 waves/CU = VGPR cap) to maximize
// residency and minimize dispatch ramp/drain.
__global__ __launch_bounds__(MAIN_THREADS) void qloss_main(
    const float* __restrict__ states, const float* __restrict__ W1,
    const float* __restrict__ b1, const float* __restrict__ W2,
    const float* __restrict__ b2, const float* __restrict__ W3,
    int n_states, double* __restrict__ partials)
{
    const int lane = threadIdx.x & 63;
    const int wave = threadIdx.x >> 6;
    const int g = lane >> 4;     // k-group 0..3
    const int r = lane & 15;     // row within A-tile / col within D-tile

    // ---- per-lane constant preload ----
    float b1r[16];
    h2 w1p[2][16];               // W1 packed as f16 pairs: (i0,i1),(i2,i3)
#pragma unroll
    for (int j = 0; j < 16; ++j) {
        const int k = 8*g + (j & 7) + 32*(j >> 3);
        b1r[j] = b1[k];
        w1p[0][j] = h2{(_Float16)W1[0*64 + k], (_Float16)W1[1*64 + k]};
        w1p[1][j] = h2{(_Float16)W1[2*64 + k], (_Float16)W1[3*64 + k]};
    }

    bf16x8 w2f[4][2];
#pragma unroll
    for (int t = 0; t < 4; ++t)
#pragma unroll
        for (int ks = 0; ks < 2; ++ks)
#pragma unroll
            for (int e = 0; e < 8; ++e) {
                const int k = 8*g + e + 32*ks;
                w2f[t][ks][e] = (__bf16)W2[k*64 + (r + 16*t)];
            }

    float b2r[4], w3r[4];
#pragma unroll
    for (int t = 0; t < 4; ++t) { b2r[t] = b2[r + 16*t]; w3r[t] = W3[r + 16*t]; }

    // Pin loop-invariant preloads in registers (R5: proven to give residency).
#pragma unroll
    for (int j = 0; j < 16; ++j) {
        asm("" : "+v"(b1r[j]));
        asm("" : "+v"(w1p[0][j]), "+v"(w1p[1][j]));
    }
#pragma unroll
    for (int t = 0; t < 4; ++t) {
        asm("" : "+v"(w2f[t][0]), "+v"(w2f[t][1]));
        asm("" : "+v"(b2r[t]), "+v"(w3r[t]));
    }

    float ps0 = 0.f, ps1 = 0.f;

    const int ntiles = n_states >> 4;
    const int waves_per_blk = blockDim.x >> 6;
    const int nwaves = gridDim.x * waves_per_blk;
    const float4* __restrict__ st4 = (const float4*)states;

    const int tile0 = blockIdx.x * waves_per_blk + wave;
    float4 xc = {0.f, 0.f, 0.f, 0.f};
    if (tile0 < ntiles) xc = st4[tile0*16 + r];   // lanes 16..63 replicate lanes 0..15

    for (int tile = tile0; tile < ntiles; tile += nwaves) {
        const int nxt = tile + nwaves;
        const int nidx = (nxt < ntiles) ? nxt : tile;
        const float4 xn = st4[nidx*16 + r];

        // layer 1: h1 = relu(x@W1 + b1) -> A-fragment, built as i32 words
        const h2 x01 = {(_Float16)xc.x, (_Float16)xc.y};
        const h2 x23 = {(_Float16)xc.z, (_Float16)xc.w};
        i32x4 aw0, aw1;
#pragma unroll
        for (int ks = 0; ks < 2; ++ks) {
#pragma unroll
            for (int w = 0; w < 4; ++w) {
                const int j0 = ks*8 + 2*w, j1 = j0 + 1;
                float t0 = __builtin_amdgcn_fdot2(x01, w1p[0][j0], b1r[j0], false);
                t0       = __builtin_amdgcn_fdot2(x23, w1p[1][j0], t0, false);
                float t1 = __builtin_amdgcn_fdot2(x01, w1p[0][j1], b1r[j1], false);
                t1       = __builtin_amdgcn_fdot2(x23, w1p[1][j1], t1, false);
                t0 = fmaxf(t0, 0.f);
                t1 = fmaxf(t1, 0.f);
                int w32;
                asm("v_cvt_pk_bf16_f32 %0, %1, %2" : "=v"(w32) : "v"(t0), "v"(t1));
                if (ks == 0) aw0[w] = w32; else aw1[w] = w32;
            }
        }
        const bf16x8 af0 = __builtin_bit_cast(bf16x8, aw0);
        const bf16x8 af1 = __builtin_bit_cast(bf16x8, aw1);

        // layer 2 (MFMA, b2 folded into acc init) + epilogue (relu * W3)
#pragma unroll
        for (int t4 = 0; t4 < 4; ++t4) {
            f32x4 acc = { b2r[t4], b2r[t4], b2r[t4], b2r[t4] };
            acc = __builtin_amdgcn_mfma_f32_16x16x32_bf16(af0, w2f[t4][0], acc, 0, 0, 0);
            acc = __builtin_amdgcn_mfma_f32_16x16x32_bf16(af1, w2f[t4][1], acc, 0, 0, 0);
            ps0 = fmaf(fmaxf(acc[0], 0.f), w3r[t4], ps0);
            ps1 = fmaf(fmaxf(acc[1], 0.f), w3r[t4], ps1);
            ps0 = fmaf(fmaxf(acc[2], 0.f), w3r[t4], ps0);
            ps1 = fmaf(fmaxf(acc[3], 0.f), w3r[t4], ps1);
        }

        xc = xn;
    }

    // ---- block reduction -> one double partial per block ----
    float psum = ps0 + ps1;
#pragma unroll
    for (int off = 32; off; off >>= 1) psum += __shfl_xor(psum, off, 64);
    __shared__ float wpart[MAIN_THREADS / 64];
    if (lane == 0) wpart[wave] = psum;
    __syncthreads();
    if (threadIdx.x == 0) {
        float s = 0.f;
#pragma unroll
        for (int i = 0; i < MAIN_THREADS / 64; ++i) s += wpart[i];
        partials[blockIdx.x] = (double)s;
    }
}

// 1 block, 256 threads: wave w computes net(e_w) in fp32; thread 0 combines.
__global__ __launch_bounds__(256) void qloss_finalize(
    const float* __restrict__ W1, const float* __restrict__ b1,
    const float* __restrict__ W2, const float* __restrict__ b2,
    const float* __restrict__ W3, const float* __restrict__ b3,
    const double* __restrict__ partials, int nparts,
    int n_states, float* __restrict__ out)
{
    const int lane = threadIdx.x & 63;
    const int wave = threadIdx.x >> 6;

    __shared__ float  dlog[4];
    __shared__ double wsum[4];

    // denominator logits: one-hot state index == wave
    float h1 = fmaxf(W1[wave*64 + lane] + b1[lane], 0.f);
    float acc = b2[lane];
    for (int k = 0; k < 64; ++k)
        acc = fmaf(__shfl(h1, k, 64), W2[k*64 + lane], acc);
    float c = fmaxf(acc, 0.f) * W3[lane];
#pragma unroll
    for (int off = 32; off; off >>= 1) c += __shfl_xor(c, off, 64);
    if (lane == 0) dlog[wave] = c + b3[0];

    // sum block partials
    double ps = 0.0;
    for (int i = threadIdx.x; i < nparts; i += blockDim.x) ps += partials[i];
#pragma unroll
    for (int off = 32; off; off >>= 1) ps += __shfl_xor(ps, off, 64);
    if (lane == 0) wsum[wave] = ps;

    __syncthreads();
    if (threadIdx.x == 0) {
        const double S = wsum[0] + wsum[1] + wsum[2] + wsum[3];
        double m = dlog[0];
        for (int i = 1; i < 4; ++i) m = fmax(m, (double)dlog[i]);
        double e = 0.0;
        for (int i = 0; i < 4; ++i) e += exp((double)dlog[i] - m);
        const double lse = m + log(e);
        const double nn = (double)n_states;
        const double logits_sum = S + nn * (double)b3[0];
        out[0] = (float)(-(logits_sum - nn * lse));
    }
}

extern "C" void kernel_launch(void* const* d_in, const int* in_sizes, int n_in,
                              void* d_out, int out_size, void* d_ws, size_t ws_size,
                              hipStream_t stream)
{
    const float* states = (const float*)d_in[0];
    const float* W1 = (const float*)d_in[1];
    const float* b1 = (const float*)d_in[2];
    const float* W2 = (const float*)d_in[3];
    const float* b2 = (const float*)d_in[4];
    const float* W3 = (const float*)d_in[5];
    const float* b3 = (const float*)d_in[6];
    float* out = (float*)d_out;

    const int n_states = in_sizes[0] / 4;

    int nb = MAIN_BLOCKS;
    const size_t max_parts = ws_size / sizeof(double);
    if ((size_t)nb > max_parts) nb = (int)max_parts;
    if (nb < 1) nb = 1;
    double* partials = (double*)d_ws;

    qloss_main<<<nb, MAIN_THREADS, 0, stream>>>(states, W1, b1, W2, b2, W3, n_states, partials);
    qloss_finalize<<<1, 256, 0, stream>>>(W1, b1, W2, b2, W3, b3, partials, nb, n_states, out);
}